// Round 7
// baseline (189.367 us; speedup 1.0000x reference)
//
#include <hip/hip_runtime.h>
#include <hip/hip_bf16.h>

// ---------------------------------------------------------------------------
// IrrepsLinear via bf16 hi/lo-split MFMA (gfx950), round 7.
// Split into 3 independent kernels (phases touch disjoint x/out columns):
//   kA: out0 = (x0 @ W0 + modal @ W0m) / sqrt(130)   [N,128] <- [N,0:128)
//   kB: out1 = einsum('nim,io', x1, W1) / 8          [N,192] <- [N,128:320)
//   kC: out2 = einsum('nim,io', x2, W2) / sqrt(32)   [N,160] <- [N,320:480)
// Each kernel: 2 barriers only (separate LDS input/output regions), so
// stage -> compute -> stream has no phase-chaining lockstep; blocks overlap.
// v = hi + lo (bf16 RNE); v*w ~ vh*wh + vl*wh + vh*wl (3 MFMAs).
// ---------------------------------------------------------------------------

typedef __attribute__((ext_vector_type(8))) short  short8;   // bf16x8 frag
typedef __attribute__((ext_vector_type(4))) float  f32x4;    // acc frag

#define NTH 256
#define BR  32

// ws layout in ushort units
#define W0H 0
#define W0L 16384
#define W1H 32768
#define W1L 36864
#define W2H 40960
#define W2L 41984
// total 43008 ushorts = 86016 bytes of d_ws

// --------------------------- split helpers ---------------------------------
__device__ __forceinline__ unsigned bc2(__hip_bfloat162 h) {
    unsigned u; __builtin_memcpy(&u, &h, 4); return u;
}

struct HL4 { uint2 h, l; };

__device__ __forceinline__ HL4 split4(float a, float b, float c, float d) {
    __hip_bfloat162 h01 = __float22bfloat162_rn({a, b});
    __hip_bfloat162 h23 = __float22bfloat162_rn({c, d});
    float ra = a - __low2float(h01),  rb = b - __high2float(h01);
    float rc = c - __low2float(h23),  rd = d - __high2float(h23);
    __hip_bfloat162 l01 = __float22bfloat162_rn({ra, rb});
    __hip_bfloat162 l23 = __float22bfloat162_rn({rc, rd});
    HL4 r;
    r.h = make_uint2(bc2(h01), bc2(h23));
    r.l = make_uint2(bc2(l01), bc2(l23));
    return r;
}

__device__ __forceinline__ void split_w(float v, unsigned short& h, unsigned short& l) {
    __hip_bfloat16 hb = __float2bfloat16(v);
    float r = v - __bfloat162float(hb);
    __hip_bfloat16 lb = __float2bfloat16(r);
    __builtin_memcpy(&h, &hb, 2);
    __builtin_memcpy(&l, &lb, 2);
}

// --------------------------- weight prep kernel ----------------------------
// B-frag order: slot s = ((ct*NKT + kt)*64 + lane)*8 + j holds W[k][col],
//   col = ct*16 + (lane&15), k = kt*32 + (lane>>4)*8 + j.
__global__ void prep_weights(const float* __restrict__ W0,
                             const float* __restrict__ W1,
                             const float* __restrict__ W2,
                             unsigned short* __restrict__ ws) {
    const int s0     = blockIdx.x * blockDim.x + threadIdx.x;
    const int STRIDE = gridDim.x * blockDim.x;
    for (int s = s0; s < 16384; s += STRIDE) {     // W0: ct 0..7, kt 0..3
        int j = s & 7, l = (s >> 3) & 63, kt = (s >> 9) & 3, ct = s >> 11;
        int col = ct * 16 + (l & 15);
        int k   = kt * 32 + (l >> 4) * 8 + j;
        unsigned short h, lo;
        split_w(W0[k * 128 + col], h, lo);
        ws[W0H + s] = h; ws[W0L + s] = lo;
    }
    for (int s = s0; s < 4096; s += STRIDE) {      // W1: ct 0..3, kt 0..1
        int j = s & 7, l = (s >> 3) & 63, kt = (s >> 9) & 1, ct = s >> 10;
        int col = ct * 16 + (l & 15);
        int k   = kt * 32 + (l >> 4) * 8 + j;
        unsigned short h, lo;
        split_w(W1[k * 64 + col], h, lo);
        ws[W1H + s] = h; ws[W1L + s] = lo;
    }
    for (int s = s0; s < 1024; s += STRIDE) {      // W2: ct 0..1, kt = 0
        int j = s & 7, l = (s >> 3) & 63, ct = s >> 9;
        int col = ct * 16 + (l & 15);
        int k   = (l >> 4) * 8 + j;
        unsigned short h, lo;
        split_w(W2[k * 32 + col], h, lo);
        ws[W2H + s] = h; ws[W2L + s] = lo;
    }
}

#define MFMA(a, b, c) __builtin_amdgcn_mfma_f32_16x16x32_bf16((a), (b), (c), 0, 0, 0)

// ============================ Kernel A : out0 ==============================
// LDS: IN bf16 hi@0 / lo@8192 ([32][128], swz (row&7)<<4)  = 16384 B
//      OUT f32 [32][132] @16384                             = 16896 B
// total 33280 B -> 4 blocks/CU at (256,4).
__global__ __launch_bounds__(NTH, 4) void kA(
    const float* __restrict__ x,
    const float* __restrict__ modal_attr,
    const float* __restrict__ W0m,
    const unsigned short* __restrict__ wsf,
    const int*   __restrict__ batch,
    float*       __restrict__ out,
    int N)
{
    __shared__ __align__(16) char ldsb[33280];
    float* ldsf = reinterpret_cast<float*>(ldsb + 16384);

    const int tid  = threadIdx.x;
    const int w    = tid >> 6;
    const int l    = tid & 63;
    const int r    = l & 15;
    const int kg   = l >> 4;
    const int rb0  = (w >> 1) * 16;
    const int ch   = w & 1;
    const int row0 = blockIdx.x * BR;
    const int arow = rb0 + r;

    float am0[4], am1[4];
    #pragma unroll
    for (int reg = 0; reg < 4; ++reg) {
        int n  = row0 + rb0 + kg * 4 + reg;
        int nc = n < N ? n : N - 1;
        int g  = batch[nc];
        am0[reg] = modal_attr[2 * g];
        am1[reg] = modal_attr[2 * g + 1];
    }

    const float4* __restrict__ x4 = reinterpret_cast<const float4*>(x);

    {   // stage+split x[:,0:128)
        const int seg = tid & 15;
        const int rr0 = tid >> 4;
        #pragma unroll
        for (int t2 = 0; t2 < 2; ++t2) {
            int rr = rr0 + 16 * t2;
            int n  = row0 + rr; n = n < N ? n : N - 1;
            const float4* src = &x4[(size_t)n * 120 + seg * 2];
            float4 a = src[0], b = src[1];
            HL4 p = split4(a.x, a.y, a.z, a.w);
            HL4 q = split4(b.x, b.y, b.z, b.w);
            int byte = (rr * 256 + seg * 16) ^ ((rr & 7) << 4);
            *reinterpret_cast<uint4*>(ldsb + byte)        = make_uint4(p.h.x, p.h.y, q.h.x, q.h.y);
            *reinterpret_cast<uint4*>(ldsb + 8192 + byte) = make_uint4(p.l.x, p.l.y, q.l.x, q.l.y);
        }
    }
    __syncthreads();

    {   // frag load + MFMA + epilogue (OUT region disjoint from IN: no bar)
        const int sw = (arow & 7) << 4;
        short8 ah[4], al[4];
        #pragma unroll
        for (int kt = 0; kt < 4; ++kt) {
            int byte = (arow * 256 + kt * 64 + kg * 16) ^ sw;
            ah[kt] = *reinterpret_cast<const short8*>(ldsb + byte);
            al[kt] = *reinterpret_cast<const short8*>(ldsb + 8192 + byte);
        }
        #pragma unroll
        for (int ci = 0; ci < 4; ++ci) {
            int ct = ch * 4 + ci;
            f32x4 acc = {0.f, 0.f, 0.f, 0.f};
            #pragma unroll
            for (int kt = 0; kt < 4; ++kt) {
                int b = ct * 4 + kt;
                short8 bh = *reinterpret_cast<const short8*>(wsf + W0H + (size_t)(b * 64 + l) * 8);
                short8 bl = *reinterpret_cast<const short8*>(wsf + W0L + (size_t)(b * 64 + l) * 8);
                acc = MFMA(ah[kt], bh, acc);
                acc = MFMA(al[kt], bh, acc);
                acc = MFMA(ah[kt], bl, acc);
            }
            int col = ct * 16 + r;
            float wm0 = W0m[col], wm1 = W0m[128 + col];
            #pragma unroll
            for (int reg = 0; reg < 4; ++reg)
                ldsf[(rb0 + kg * 4 + reg) * 132 + col] =
                    (acc[reg] + am0[reg] * wm0 + am1[reg] * wm1) * 0.08770580193070293f;
        }
    }
    __syncthreads();

    {   // stream out0: 32 rows x 128 f32, coalesced float4
        #pragma unroll
        for (int j = 0; j < 4; ++j) {
            int idx = tid + j * NTH;
            int row = idx >> 5, c4 = idx & 31;
            int n   = row0 + row;
            if (n < N)
                *reinterpret_cast<float4*>(out + (size_t)n * 480 + c4 * 4) =
                    *reinterpret_cast<const float4*>(ldsf + row * 132 + c4 * 4);
        }
    }
}

// ============================ Kernel B : out1 ==============================
// LDS: IN bf16 hi 3x4096@0 / lo @12288 ([m][32][64], swz (row&7)<<4) = 24576 B
//      OUT f32 [32][196] @24576                                      = 25088 B
// total 49664 B -> 3 blocks/CU at (256,3).
__global__ __launch_bounds__(NTH, 3) void kB(
    const float* __restrict__ x,
    const unsigned short* __restrict__ wsf,
    float*       __restrict__ out,
    int N)
{
    __shared__ __align__(16) char ldsb[49664];
    float* ldsf = reinterpret_cast<float*>(ldsb + 24576);

    const int tid  = threadIdx.x;
    const int w    = tid >> 6;
    const int l    = tid & 63;
    const int r    = l & 15;
    const int kg   = l >> 4;
    const int rb0  = (w >> 1) * 16;
    const int ch   = w & 1;
    const int row0 = blockIdx.x * BR;
    const int arow = rb0 + r;

    const float4* __restrict__ x4 = reinterpret_cast<const float4*>(x);

    {   // stage+split x[:,128:320) de-interleaved by m
        const int ig  = tid & 15;
        const int rr0 = tid >> 4;
        #pragma unroll
        for (int t2 = 0; t2 < 2; ++t2) {
            int rr = rr0 + 16 * t2;
            int n  = row0 + rr; n = n < N ? n : N - 1;
            const float4* src = &x4[(size_t)n * 120 + 32 + ig * 3];
            float4 f0 = src[0], f1 = src[1], f2 = src[2];
            HL4 s0 = split4(f0.x, f0.w, f1.z, f2.y);   // m=0
            HL4 s1 = split4(f0.y, f1.x, f1.w, f2.z);   // m=1
            HL4 s2 = split4(f0.z, f1.y, f2.x, f2.w);   // m=2
            int rbyte = (rr * 128 + ig * 8) ^ ((rr & 7) << 4);
            *reinterpret_cast<uint2*>(ldsb + 0 * 4096 + rbyte)         = s0.h;
            *reinterpret_cast<uint2*>(ldsb + 1 * 4096 + rbyte)         = s1.h;
            *reinterpret_cast<uint2*>(ldsb + 2 * 4096 + rbyte)         = s2.h;
            *reinterpret_cast<uint2*>(ldsb + 12288 + 0 * 4096 + rbyte) = s0.l;
            *reinterpret_cast<uint2*>(ldsb + 12288 + 1 * 4096 + rbyte) = s1.l;
            *reinterpret_cast<uint2*>(ldsb + 12288 + 2 * 4096 + rbyte) = s2.l;
        }
    }
    __syncthreads();

    {
        const int sw = (arow & 7) << 4;
        short8 ah1[3][2], al1[3][2];
        #pragma unroll
        for (int m = 0; m < 3; ++m) {
            #pragma unroll
            for (int kt = 0; kt < 2; ++kt) {
                int byte = (arow * 128 + kt * 64 + kg * 16) ^ sw;
                ah1[m][kt] = *reinterpret_cast<const short8*>(ldsb + m * 4096 + byte);
                al1[m][kt] = *reinterpret_cast<const short8*>(ldsb + 12288 + m * 4096 + byte);
            }
        }
        #pragma unroll
        for (int ci = 0; ci < 2; ++ci) {
            int ct = ch * 2 + ci;
            short8 bh[2], bl[2];
            #pragma unroll
            for (int kt = 0; kt < 2; ++kt) {
                int b = ct * 2 + kt;
                bh[kt] = *reinterpret_cast<const short8*>(wsf + W1H + (size_t)(b * 64 + l) * 8);
                bl[kt] = *reinterpret_cast<const short8*>(wsf + W1L + (size_t)(b * 64 + l) * 8);
            }
            #pragma unroll
            for (int m = 0; m < 3; ++m) {
                f32x4 acc = {0.f, 0.f, 0.f, 0.f};
                #pragma unroll
                for (int kt = 0; kt < 2; ++kt) {
                    acc = MFMA(ah1[m][kt], bh[kt], acc);
                    acc = MFMA(al1[m][kt], bh[kt], acc);
                    acc = MFMA(ah1[m][kt], bl[kt], acc);
                }
                int col = 3 * (ct * 16 + r) + m;
                #pragma unroll
                for (int reg = 0; reg < 4; ++reg)
                    ldsf[(rb0 + kg * 4 + reg) * 196 + col] = acc[reg] * 0.125f;
            }
        }
    }
    __syncthreads();

    {   // stream out1: 32 rows x 192 f32
        #pragma unroll
        for (int j = 0; j < 6; ++j) {
            int idx = tid + j * NTH;
            int row = idx / 48, c4 = idx - row * 48;
            int n   = row0 + row;
            if (n < N)
                *reinterpret_cast<float4*>(out + (size_t)n * 480 + 128 + c4 * 4) =
                    *reinterpret_cast<const float4*>(ldsf + row * 196 + c4 * 4);
        }
    }
}

// ============================ Kernel C : out2 ==============================
// LDS: IN bf16 hi 5x2048@0 / lo @10240 ([m][32][32], swz (row&3)<<4) = 20480 B
//      OUT f32 [32][164] @20480                                      = 20992 B
// total 41472 B -> 3 blocks/CU at (256,3).
__global__ __launch_bounds__(NTH, 3) void kC(
    const float* __restrict__ x,
    const unsigned short* __restrict__ wsf,
    float*       __restrict__ out,
    int N)
{
    __shared__ __align__(16) char ldsb[41472];
    float* ldsf = reinterpret_cast<float*>(ldsb + 20480);

    const int tid  = threadIdx.x;
    const int w    = tid >> 6;
    const int l    = tid & 63;
    const int r    = l & 15;
    const int kg   = l >> 4;
    const int rb0  = (w >> 1) * 16;
    const int ch   = w & 1;
    const int row0 = blockIdx.x * BR;
    const int arow = rb0 + r;

    const float4* __restrict__ x4 = reinterpret_cast<const float4*>(x);

    {   // stage+split x[:,320:480) de-interleaved by m
        int rr = tid >> 3, ig = tid & 7;
        int n  = row0 + rr; n = n < N ? n : N - 1;
        const float4* src = &x4[(size_t)n * 120 + 80 + ig * 5];
        float f[20];
        #pragma unroll
        for (int q = 0; q < 5; ++q) {
            float4 v = src[q];
            f[q * 4 + 0] = v.x; f[q * 4 + 1] = v.y; f[q * 4 + 2] = v.z; f[q * 4 + 3] = v.w;
        }
        int rbyte = (rr * 64 + ig * 8) ^ ((rr & 3) << 4);
        #pragma unroll
        for (int m = 0; m < 5; ++m) {
            HL4 s = split4(f[m], f[5 + m], f[10 + m], f[15 + m]);
            *reinterpret_cast<uint2*>(ldsb + m * 2048 + rbyte)         = s.h;
            *reinterpret_cast<uint2*>(ldsb + 10240 + m * 2048 + rbyte) = s.l;
        }
    }
    __syncthreads();

    {
        const int sw2 = (arow & 3) << 4;
        short8 ah2[5], al2[5];
        #pragma unroll
        for (int m = 0; m < 5; ++m) {
            int byte = (arow * 64 + kg * 16) ^ sw2;
            ah2[m] = *reinterpret_cast<const short8*>(ldsb + m * 2048 + byte);
            al2[m] = *reinterpret_cast<const short8*>(ldsb + 10240 + m * 2048 + byte);
        }
        int ct = ch;
        short8 bh = *reinterpret_cast<const short8*>(wsf + W2H + (size_t)(ct * 64 + l) * 8);
        short8 bl = *reinterpret_cast<const short8*>(wsf + W2L + (size_t)(ct * 64 + l) * 8);
        #pragma unroll
        for (int m = 0; m < 5; ++m) {
            f32x4 acc = {0.f, 0.f, 0.f, 0.f};
            acc = MFMA(ah2[m], bh, acc);
            acc = MFMA(al2[m], bh, acc);
            acc = MFMA(ah2[m], bl, acc);
            int col = 5 * (ct * 16 + r) + m;
            #pragma unroll
            for (int reg = 0; reg < 4; ++reg)
                ldsf[(rb0 + kg * 4 + reg) * 164 + col] = acc[reg] * 0.17677669529663687f;
        }
    }
    __syncthreads();

    {   // stream out2: 32 rows x 160 f32
        #pragma unroll
        for (int j = 0; j < 5; ++j) {
            int idx = tid + j * NTH;
            int row = idx / 40, c4 = idx - row * 40;
            int n   = row0 + row;
            if (n < N)
                *reinterpret_cast<float4*>(out + (size_t)n * 480 + 320 + c4 * 4) =
                    *reinterpret_cast<const float4*>(ldsf + row * 164 + c4 * 4);
        }
    }
}

extern "C" void kernel_launch(void* const* d_in, const int* in_sizes, int n_in,
                              void* d_out, int out_size, void* d_ws, size_t ws_size,
                              hipStream_t stream) {
    const float* x     = (const float*)d_in[0];
    const float* modal = (const float*)d_in[1];
    const float* W0    = (const float*)d_in[2];
    const float* W0m   = (const float*)d_in[3];
    const float* W1    = (const float*)d_in[4];
    const float* W2    = (const float*)d_in[5];
    const int*   batch = (const int*)d_in[6];
    float* out = (float*)d_out;
    unsigned short* ws = (unsigned short*)d_ws;   // needs 86016 B

    const int N    = in_sizes[6];                 // 200000
    const int grid = (N + BR - 1) / BR;           // 6250 blocks

    prep_weights<<<84, NTH, 0, stream>>>(W0, W1, W2, ws);
    kA<<<grid, NTH, 0, stream>>>(x, modal, W0m, ws, batch, out, N);
    kB<<<grid, NTH, 0, stream>>>(x, ws, out, N);
    kC<<<grid, NTH, 0, stream>>>(x, ws, out, N);
}

// Round 8
// 159.465 us; speedup vs baseline: 1.1875x; 1.1875x over previous
//
#include <hip/hip_runtime.h>
#include <hip/hip_bf16.h>

// ---------------------------------------------------------------------------
// IrrepsLinear via bf16 hi/lo-split MFMA (gfx950), round 8.
//   out0 = (x0 @ W0 + modal @ W0m) / sqrt(130)      x0: [N,128], W0: 128x128
//   out1 = einsum('nim,io', x1, W1) / 8             x1: [N,64,3], W1: 64x64
//   out2 = einsum('nim,io', x2, W2) / sqrt(32)      x2: [N,32,5], W2: 32x32
// v = hi + lo (bf16 RNE); v*w ~ vh*wh + vl*wh + vh*wl (3 MFMAs).
// Round-8 deltas vs round 6 (164us):  [r7 3-kernel split regressed: 189us,
// lost full-row DRAM locality -> monolith restored]
//   - Separate IN (24576B) / OUT (25088B) LDS regions: 12 barriers -> 6;
//     stream(P) overlaps stage(P+1) in one slot (disjoint regions).
//   - T14 issue-early: phase-B x-loads issued before bar1 (fly under
//     compute A); phase-C loads issued in stream-A slot (fly under B).
//   - LDS 49664B -> 3 blocks/CU, __launch_bounds__(256,3) (VGPR cap ~168).
// ---------------------------------------------------------------------------

typedef __attribute__((ext_vector_type(8))) short  short8;   // bf16x8 frag
typedef __attribute__((ext_vector_type(4))) float  f32x4;    // acc frag

#define NTH 256
#define BR  32

// ws layout in ushort units
#define W0H 0
#define W0L 16384
#define W1H 32768
#define W1L 36864
#define W2H 40960
#define W2L 41984
// total 43008 ushorts = 86016 bytes of d_ws

// LDS regions (bytes)
#define IN0   0        // input tiles (max 24576: phase B)
#define OUT0  24576    // fp32 output tiles (max 25088: phase B)

// --------------------------- split helpers ---------------------------------
__device__ __forceinline__ unsigned bc2(__hip_bfloat162 h) {
    unsigned u; __builtin_memcpy(&u, &h, 4); return u;
}

struct HL4 { uint2 h, l; };

__device__ __forceinline__ HL4 split4(float a, float b, float c, float d) {
    __hip_bfloat162 h01 = __float22bfloat162_rn({a, b});
    __hip_bfloat162 h23 = __float22bfloat162_rn({c, d});
    float ra = a - __low2float(h01),  rb = b - __high2float(h01);
    float rc = c - __low2float(h23),  rd = d - __high2float(h23);
    __hip_bfloat162 l01 = __float22bfloat162_rn({ra, rb});
    __hip_bfloat162 l23 = __float22bfloat162_rn({rc, rd});
    HL4 r;
    r.h = make_uint2(bc2(h01), bc2(h23));
    r.l = make_uint2(bc2(l01), bc2(l23));
    return r;
}

__device__ __forceinline__ void split_w(float v, unsigned short& h, unsigned short& l) {
    __hip_bfloat16 hb = __float2bfloat16(v);
    float r = v - __bfloat162float(hb);
    __hip_bfloat16 lb = __float2bfloat16(r);
    __builtin_memcpy(&h, &hb, 2);
    __builtin_memcpy(&l, &lb, 2);
}

// --------------------------- weight prep kernel ----------------------------
// B-frag order: slot s = ((ct*NKT + kt)*64 + lane)*8 + j holds W[k][col],
//   col = ct*16 + (lane&15), k = kt*32 + (lane>>4)*8 + j.
__global__ void prep_weights(const float* __restrict__ W0,
                             const float* __restrict__ W1,
                             const float* __restrict__ W2,
                             unsigned short* __restrict__ ws) {
    const int s0     = blockIdx.x * blockDim.x + threadIdx.x;
    const int STRIDE = gridDim.x * blockDim.x;
    for (int s = s0; s < 16384; s += STRIDE) {     // W0: ct 0..7, kt 0..3
        int j = s & 7, l = (s >> 3) & 63, kt = (s >> 9) & 3, ct = s >> 11;
        int col = ct * 16 + (l & 15);
        int k   = kt * 32 + (l >> 4) * 8 + j;
        unsigned short h, lo;
        split_w(W0[k * 128 + col], h, lo);
        ws[W0H + s] = h; ws[W0L + s] = lo;
    }
    for (int s = s0; s < 4096; s += STRIDE) {      // W1: ct 0..3, kt 0..1
        int j = s & 7, l = (s >> 3) & 63, kt = (s >> 9) & 1, ct = s >> 10;
        int col = ct * 16 + (l & 15);
        int k   = kt * 32 + (l >> 4) * 8 + j;
        unsigned short h, lo;
        split_w(W1[k * 64 + col], h, lo);
        ws[W1H + s] = h; ws[W1L + s] = lo;
    }
    for (int s = s0; s < 1024; s += STRIDE) {      // W2: ct 0..1, kt = 0
        int j = s & 7, l = (s >> 3) & 63, ct = s >> 9;
        int col = ct * 16 + (l & 15);
        int k   = (l >> 4) * 8 + j;
        unsigned short h, lo;
        split_w(W2[k * 32 + col], h, lo);
        ws[W2H + s] = h; ws[W2L + s] = lo;
    }
}

#define MFMA(a, b, c) __builtin_amdgcn_mfma_f32_16x16x32_bf16((a), (b), (c), 0, 0, 0)

// ------------------------------ main kernel --------------------------------
// 4 waves/block; wave w: rows rb0=(w>>1)*16, col-half ch=w&1.
// IN  region: A hi@0/lo@8192 ([32][128]bf16, swz (row&7)<<4)
//             B hi m*4096@0 / lo @12288 ([m][32][64], swz (row&7)<<4)
//             C hi m*2048@0 / lo @10240 ([m][32][32], swz (row&3)<<4)
// OUT region: A f32 [32][132]; B f32 [32][196]; C f32 [32][164]
__global__ __launch_bounds__(NTH, 3) void irreps_mfma_kernel(
    const float* __restrict__ x,
    const float* __restrict__ modal_attr,
    const float* __restrict__ W0m,
    const unsigned short* __restrict__ wsf,
    const int*   __restrict__ batch,
    float*       __restrict__ out,
    int N)
{
    __shared__ __align__(16) char ldsb[49664];
    char*  inb  = ldsb + IN0;
    float* ldsf = reinterpret_cast<float*>(ldsb + OUT0);

    const int tid  = threadIdx.x;
    const int w    = tid >> 6;
    const int l    = tid & 63;
    const int r    = l & 15;
    const int kg   = l >> 4;
    const int rb0  = (w >> 1) * 16;
    const int ch   = w & 1;
    const int row0 = blockIdx.x * BR;
    const int arow = rb0 + r;

    float am0[4], am1[4];
    #pragma unroll
    for (int reg = 0; reg < 4; ++reg) {
        int n  = row0 + rb0 + kg * 4 + reg;
        int nc = n < N ? n : N - 1;
        int g  = batch[nc];
        am0[reg] = modal_attr[2 * g];
        am1[reg] = modal_attr[2 * g + 1];
    }

    const float4* __restrict__ x4 = reinterpret_cast<const float4*>(x);

    // ---- stage+split phase-A input: x[:,0:128) ----
    {
        const int seg = tid & 15;
        const int rr0 = tid >> 4;
        #pragma unroll
        for (int t2 = 0; t2 < 2; ++t2) {
            int rr = rr0 + 16 * t2;
            int n  = row0 + rr; n = n < N ? n : N - 1;
            const float4* src = &x4[(size_t)n * 120 + seg * 2];
            float4 a = src[0], b = src[1];
            HL4 p = split4(a.x, a.y, a.z, a.w);
            HL4 q = split4(b.x, b.y, b.z, b.w);
            int byte = (rr * 256 + seg * 16) ^ ((rr & 7) << 4);
            *reinterpret_cast<uint4*>(inb + byte)        = make_uint4(p.h.x, p.h.y, q.h.x, q.h.y);
            *reinterpret_cast<uint4*>(inb + 8192 + byte) = make_uint4(p.l.x, p.l.y, q.l.x, q.l.y);
        }
    }

    // ---- T14: issue phase-B global loads NOW (fly under compute A) ----
    float4 bld[2][3];
    {
        const int ig  = tid & 15;
        const int rr0 = tid >> 4;
        #pragma unroll
        for (int t2 = 0; t2 < 2; ++t2) {
            int rr = rr0 + 16 * t2;
            int n  = row0 + rr; n = n < N ? n : N - 1;
            const float4* src = &x4[(size_t)n * 120 + 32 + ig * 3];
            bld[t2][0] = src[0]; bld[t2][1] = src[1]; bld[t2][2] = src[2];
        }
    }
    __syncthreads();                                            // bar 1

    // ---- compute A: frags from IN, MFMA, epilogue -> OUT ----
    {
        const int sw = (arow & 7) << 4;
        short8 ah[4], al[4];
        #pragma unroll
        for (int kt = 0; kt < 4; ++kt) {
            int byte = (arow * 256 + kt * 64 + kg * 16) ^ sw;
            ah[kt] = *reinterpret_cast<const short8*>(inb + byte);
            al[kt] = *reinterpret_cast<const short8*>(inb + 8192 + byte);
        }
        #pragma unroll
        for (int ci = 0; ci < 4; ++ci) {
            int ct = ch * 4 + ci;
            f32x4 acc = {0.f, 0.f, 0.f, 0.f};
            #pragma unroll
            for (int kt = 0; kt < 4; ++kt) {
                int b = ct * 4 + kt;
                short8 bh = *reinterpret_cast<const short8*>(wsf + W0H + (size_t)(b * 64 + l) * 8);
                short8 bl = *reinterpret_cast<const short8*>(wsf + W0L + (size_t)(b * 64 + l) * 8);
                acc = MFMA(ah[kt], bh, acc);
                acc = MFMA(al[kt], bh, acc);
                acc = MFMA(ah[kt], bl, acc);
            }
            int col = ct * 16 + r;
            float wm0 = W0m[col], wm1 = W0m[128 + col];
            #pragma unroll
            for (int reg = 0; reg < 4; ++reg)
                ldsf[(rb0 + kg * 4 + reg) * 132 + col] =
                    (acc[reg] + am0[reg] * wm0 + am1[reg] * wm1) * 0.08770580193070293f;
        }
    }
    __syncthreads();                                            // bar 2

    // ---- slot: stream A (OUT)  ||  split+write IN_B  ||  issue C loads ----
    {
        const int ig  = tid & 15;
        const int rr0 = tid >> 4;
        #pragma unroll
        for (int t2 = 0; t2 < 2; ++t2) {
            int rr = rr0 + 16 * t2;
            float4 f0 = bld[t2][0], f1 = bld[t2][1], f2 = bld[t2][2];
            HL4 s0 = split4(f0.x, f0.w, f1.z, f2.y);   // m=0
            HL4 s1 = split4(f0.y, f1.x, f1.w, f2.z);   // m=1
            HL4 s2 = split4(f0.z, f1.y, f2.x, f2.w);   // m=2
            int rbyte = (rr * 128 + ig * 8) ^ ((rr & 7) << 4);
            *reinterpret_cast<uint2*>(inb + 0 * 4096 + rbyte)         = s0.h;
            *reinterpret_cast<uint2*>(inb + 1 * 4096 + rbyte)         = s1.h;
            *reinterpret_cast<uint2*>(inb + 2 * 4096 + rbyte)         = s2.h;
            *reinterpret_cast<uint2*>(inb + 12288 + 0 * 4096 + rbyte) = s0.l;
            *reinterpret_cast<uint2*>(inb + 12288 + 1 * 4096 + rbyte) = s1.l;
            *reinterpret_cast<uint2*>(inb + 12288 + 2 * 4096 + rbyte) = s2.l;
        }
    }
    float4 cld[5];
    {   // T14: issue phase-C loads (fly under compute B)
        int rr = tid >> 3, ig = tid & 7;
        int n  = row0 + rr; n = n < N ? n : N - 1;
        const float4* src = &x4[(size_t)n * 120 + 80 + ig * 5];
        #pragma unroll
        for (int q = 0; q < 5; ++q) cld[q] = src[q];
    }
    {   // stream out0: 32 rows x 128 f32, coalesced float4
        #pragma unroll
        for (int j = 0; j < 4; ++j) {
            int idx = tid + j * NTH;
            int row = idx >> 5, c4 = idx & 31;
            int n   = row0 + row;
            if (n < N)
                *reinterpret_cast<float4*>(out + (size_t)n * 480 + c4 * 4) =
                    *reinterpret_cast<const float4*>(ldsf + row * 132 + c4 * 4);
        }
    }
    __syncthreads();                                            // bar 3

    // ---- compute B ----
    {
        const int sw = (arow & 7) << 4;
        short8 ah1[3][2], al1[3][2];
        #pragma unroll
        for (int m = 0; m < 3; ++m) {
            #pragma unroll
            for (int kt = 0; kt < 2; ++kt) {
                int byte = (arow * 128 + kt * 64 + kg * 16) ^ sw;
                ah1[m][kt] = *reinterpret_cast<const short8*>(inb + m * 4096 + byte);
                al1[m][kt] = *reinterpret_cast<const short8*>(inb + 12288 + m * 4096 + byte);
            }
        }
        #pragma unroll
        for (int ci = 0; ci < 2; ++ci) {
            int ct = ch * 2 + ci;
            short8 bh[2], bl[2];
            #pragma unroll
            for (int kt = 0; kt < 2; ++kt) {
                int b = ct * 2 + kt;
                bh[kt] = *reinterpret_cast<const short8*>(wsf + W1H + (size_t)(b * 64 + l) * 8);
                bl[kt] = *reinterpret_cast<const short8*>(wsf + W1L + (size_t)(b * 64 + l) * 8);
            }
            #pragma unroll
            for (int m = 0; m < 3; ++m) {
                f32x4 acc = {0.f, 0.f, 0.f, 0.f};
                #pragma unroll
                for (int kt = 0; kt < 2; ++kt) {
                    acc = MFMA(ah1[m][kt], bh[kt], acc);
                    acc = MFMA(al1[m][kt], bh[kt], acc);
                    acc = MFMA(ah1[m][kt], bl[kt], acc);
                }
                int col = 3 * (ct * 16 + r) + m;
                #pragma unroll
                for (int reg = 0; reg < 4; ++reg)
                    ldsf[(rb0 + kg * 4 + reg) * 196 + col] = acc[reg] * 0.125f;
            }
        }
    }
    __syncthreads();                                            // bar 4

    // ---- slot: stream B (OUT)  ||  split+write IN_C ----
    {
        int rr = tid >> 3, ig = tid & 7;
        float f[20];
        #pragma unroll
        for (int q = 0; q < 5; ++q) {
            float4 v = cld[q];
            f[q * 4 + 0] = v.x; f[q * 4 + 1] = v.y; f[q * 4 + 2] = v.z; f[q * 4 + 3] = v.w;
        }
        int rbyte = (rr * 64 + ig * 8) ^ ((rr & 3) << 4);
        #pragma unroll
        for (int m = 0; m < 5; ++m) {
            HL4 s = split4(f[m], f[5 + m], f[10 + m], f[15 + m]);
            *reinterpret_cast<uint2*>(inb + m * 2048 + rbyte)         = s.h;
            *reinterpret_cast<uint2*>(inb + 10240 + m * 2048 + rbyte) = s.l;
        }
    }
    {   // stream out1: 32 rows x 192 f32
        #pragma unroll
        for (int j = 0; j < 6; ++j) {
            int idx = tid + j * NTH;
            int row = idx / 48, c4 = idx - row * 48;
            int n   = row0 + row;
            if (n < N)
                *reinterpret_cast<float4*>(out + (size_t)n * 480 + 128 + c4 * 4) =
                    *reinterpret_cast<const float4*>(ldsf + row * 196 + c4 * 4);
        }
    }
    __syncthreads();                                            // bar 5

    // ---- compute C ----
    {
        const int sw2 = (arow & 3) << 4;
        short8 ah2[5], al2[5];
        #pragma unroll
        for (int m = 0; m < 5; ++m) {
            int byte = (arow * 64 + kg * 16) ^ sw2;
            ah2[m] = *reinterpret_cast<const short8*>(inb + m * 2048 + byte);
            al2[m] = *reinterpret_cast<const short8*>(inb + 10240 + m * 2048 + byte);
        }
        int ct = ch;
        short8 bh = *reinterpret_cast<const short8*>(wsf + W2H + (size_t)(ct * 64 + l) * 8);
        short8 bl = *reinterpret_cast<const short8*>(wsf + W2L + (size_t)(ct * 64 + l) * 8);
        #pragma unroll
        for (int m = 0; m < 5; ++m) {
            f32x4 acc = {0.f, 0.f, 0.f, 0.f};
            acc = MFMA(ah2[m], bh, acc);
            acc = MFMA(al2[m], bh, acc);
            acc = MFMA(ah2[m], bl, acc);
            int col = 5 * (ct * 16 + r) + m;
            #pragma unroll
            for (int reg = 0; reg < 4; ++reg)
                ldsf[(rb0 + kg * 4 + reg) * 164 + col] = acc[reg] * 0.17677669529663687f;
        }
    }
    __syncthreads();                                            // bar 6

    {   // stream out2: 32 rows x 160 f32
        #pragma unroll
        for (int j = 0; j < 5; ++j) {
            int idx = tid + j * NTH;
            int row = idx / 40, c4 = idx - row * 40;
            int n   = row0 + row;
            if (n < N)
                *reinterpret_cast<float4*>(out + (size_t)n * 480 + 320 + c4 * 4) =
                    *reinterpret_cast<const float4*>(ldsf + row * 164 + c4 * 4);
        }
    }
}

extern "C" void kernel_launch(void* const* d_in, const int* in_sizes, int n_in,
                              void* d_out, int out_size, void* d_ws, size_t ws_size,
                              hipStream_t stream) {
    const float* x     = (const float*)d_in[0];
    const float* modal = (const float*)d_in[1];
    const float* W0    = (const float*)d_in[2];
    const float* W0m   = (const float*)d_in[3];
    const float* W1    = (const float*)d_in[4];
    const float* W2    = (const float*)d_in[5];
    const int*   batch = (const int*)d_in[6];
    float* out = (float*)d_out;
    unsigned short* ws = (unsigned short*)d_ws;   // needs 86016 B

    const int N    = in_sizes[6];                 // 200000
    const int grid = (N + BR - 1) / BR;           // 6250 blocks

    prep_weights<<<84, NTH, 0, stream>>>(W0, W1, W2, ws);
    irreps_mfma_kernel<<<grid, NTH, 0, stream>>>(x, modal, W0m, ws, batch, out, N);
}